// Round 1
// baseline (376.118 us; speedup 1.0000x reference)
//
#include <hip/hip_runtime.h>
#include <math.h>

#define FEAT 128   // IN_FEAT == H_FEAT == 128 (fixed by reference)

// ---------------- softmax over gathered mask ----------------

__global__ void k_gather_max(const float* __restrict__ mask, const int* __restrict__ ids,
                             float* __restrict__ mraw, float* __restrict__ pmax, int n) {
  int i = blockIdx.x * 256 + threadIdx.x;
  float v = -INFINITY;
  if (i < n) { v = mask[ids[i]]; mraw[i] = v; }
#pragma unroll
  for (int o = 32; o >= 1; o >>= 1) v = fmaxf(v, __shfl_xor(v, o, 64));
  __shared__ float s[4];
  if ((threadIdx.x & 63) == 0) s[threadIdx.x >> 6] = v;
  __syncthreads();
  if (threadIdx.x == 0) pmax[blockIdx.x] = fmaxf(fmaxf(s[0], s[1]), fmaxf(s[2], s[3]));
}

__global__ void k_reduce_max(const float* __restrict__ p, float* __restrict__ out, int n) {
  __shared__ float s[1024];
  float v = -INFINITY;
  for (int i = threadIdx.x; i < n; i += 1024) v = fmaxf(v, p[i]);
  s[threadIdx.x] = v;
  __syncthreads();
  for (int o = 512; o >= 1; o >>= 1) {
    if (threadIdx.x < o) s[threadIdx.x] = fmaxf(s[threadIdx.x], s[threadIdx.x + o]);
    __syncthreads();
  }
  if (threadIdx.x == 0) out[0] = s[0];
}

__global__ void k_exp_sum(float* __restrict__ mraw, const float* __restrict__ gmax,
                          float* __restrict__ psum, int n) {
  int i = blockIdx.x * 256 + threadIdx.x;
  float v = 0.f;
  if (i < n) { v = expf(mraw[i] - gmax[0]); mraw[i] = v; }
#pragma unroll
  for (int o = 32; o >= 1; o >>= 1) v += __shfl_xor(v, o, 64);
  __shared__ float s[4];
  if ((threadIdx.x & 63) == 0) s[threadIdx.x >> 6] = v;
  __syncthreads();
  if (threadIdx.x == 0) psum[blockIdx.x] = (s[0] + s[1]) + (s[2] + s[3]);
}

__global__ void k_reduce_sum(const float* __restrict__ p, float* __restrict__ out, int n) {
  __shared__ float s[1024];
  float v = 0.f;
  for (int i = threadIdx.x; i < n; i += 1024) v += p[i];
  s[threadIdx.x] = v;
  __syncthreads();
  for (int o = 512; o >= 1; o >>= 1) {
    if (threadIdx.x < o) s[threadIdx.x] += s[threadIdx.x + o];
    __syncthreads();
  }
  if (threadIdx.x == 0) out[0] = 1.0f / s[0];   // store inverse
}

__global__ void k_normalize(float* __restrict__ mraw, const float* __restrict__ ginv, int n) {
  int i = blockIdx.x * 256 + threadIdx.x;
  if (i < n) mraw[i] *= ginv[0];
}

// ---------------- CSR build ----------------

__global__ void k_deg(const int* __restrict__ ed, int* __restrict__ deg, int n) {
  int i = blockIdx.x * 256 + threadIdx.x;
  if (i < n) atomicAdd(&deg[ed[i]], 1);
}

__global__ __launch_bounds__(1024) void k_scan(const int* __restrict__ cnt,
                                               int* __restrict__ rp, int n) {
  __shared__ int wsum[16];
  __shared__ int cbase;
  int t = threadIdx.x, lane = t & 63, wid = t >> 6;
  if (t == 0) cbase = 0;
  __syncthreads();
  for (int base = 0; base < n; base += 8192) {
    int v[8];
    int tot = 0;
    int idx0 = base + t * 8;
#pragma unroll
    for (int j = 0; j < 8; j++) { int ix = idx0 + j; v[j] = (ix < n) ? cnt[ix] : 0; tot += v[j]; }
    int x = tot;
#pragma unroll
    for (int o = 1; o < 64; o <<= 1) { int y = __shfl_up(x, o, 64); if (lane >= o) x += y; }
    if (lane == 63) wsum[wid] = x;
    __syncthreads();
    if (t < 16) {
      int w = wsum[t];
#pragma unroll
      for (int o = 1; o < 16; o <<= 1) { int y = __shfl_up(w, o, 64); if (t >= o) w += y; }
      wsum[t] = w;  // inclusive over wave sums
    }
    __syncthreads();
    int wexcl = (wid == 0) ? 0 : wsum[wid - 1];
    int run = cbase + wexcl + (x - tot);
#pragma unroll
    for (int j = 0; j < 8; j++) { int ix = idx0 + j; if (ix < n) rp[ix] = run; run += v[j]; }
    __syncthreads();
    if (t == 0) cbase += wsum[15];
    __syncthreads();
  }
  if (t == 0) rp[n] = cbase;
}

__global__ void k_scatter(const int* __restrict__ es, const int* __restrict__ ed,
                          const int* __restrict__ rp, int* __restrict__ cur,
                          int* __restrict__ csr, int n) {
  int i = blockIdx.x * 256 + threadIdx.x;
  if (i < n) {
    int d = ed[i];
    int p = atomicAdd(&cur[d], 1);
    csr[rp[d] + p] = es[i];
  }
}

// ---------------- per-dst gather + scale + mean ----------------

__global__ __launch_bounds__(64) void k_agg(const int* __restrict__ rp, const int* __restrict__ csr,
                                            const float* __restrict__ h, const float* __restrict__ mv,
                                            float* __restrict__ rst) {
  int d = blockIdx.x;
  int beg = rp[d], end = rp[d + 1];
  int lane = threadIdx.x;
  float ax = 0.f, ay = 0.f;
  int e = beg;
  for (; e + 4 <= end; e += 4) {
    int s0 = csr[e + 0], s1 = csr[e + 1], s2 = csr[e + 2], s3 = csr[e + 3];
    float m0 = mv[s0], m1 = mv[s1], m2 = mv[s2], m3 = mv[s3];
    float2 v0 = *(const float2*)(h + (size_t)s0 * FEAT + lane * 2);
    float2 v1 = *(const float2*)(h + (size_t)s1 * FEAT + lane * 2);
    float2 v2 = *(const float2*)(h + (size_t)s2 * FEAT + lane * 2);
    float2 v3 = *(const float2*)(h + (size_t)s3 * FEAT + lane * 2);
    ax += v0.x * m0; ay += v0.y * m0;
    ax += v1.x * m1; ay += v1.y * m1;
    ax += v2.x * m2; ay += v2.y * m2;
    ax += v3.x * m3; ay += v3.y * m3;
  }
  for (; e < end; ++e) {
    int s = csr[e];
    float m = mv[s];
    float2 v = *(const float2*)(h + (size_t)s * FEAT + lane * 2);
    ax += v.x * m; ay += v.y * m;
  }
  float inv = 1.0f / fmaxf((float)(end - beg), 1.0f);
  float2 o;
  o.x = ax * inv;
  o.y = ay * inv;
  *(float2*)(rst + (size_t)d * FEAT + lane * 2) = o;
}

// ---------------- in-place dense transform: out = rst @ W + b ----------------

__global__ __launch_bounds__(256) void k_gemm(float* __restrict__ out, const float* __restrict__ W,
                                              const float* __restrict__ b, int nd) {
  __shared__ float Ws[FEAT * FEAT];   // 64 KiB
  __shared__ float Rs[32][FEAT];      // 16 KiB
  int t = threadIdx.x;
  for (int i = t; i < FEAT * FEAT; i += 256) Ws[i] = W[i];
  int r0 = blockIdx.x * 32;
  int rows = min(32, nd - r0);
  for (int i = t; i < rows * FEAT; i += 256) Rs[i >> 7][i & 127] = out[(size_t)r0 * FEAT + i];
  __syncthreads();

  int c0 = (t & 31) * 4;      // 4 output columns
  int rg = (t >> 5) * 4;      // 4 output rows
  float acc[4][4];
  float4 bb = *(const float4*)(b + c0);
#pragma unroll
  for (int i = 0; i < 4; i++) { acc[i][0] = bb.x; acc[i][1] = bb.y; acc[i][2] = bb.z; acc[i][3] = bb.w; }

  for (int k = 0; k < FEAT; k++) {
    float4 wv = *(const float4*)(&Ws[k * FEAT + c0]);
#pragma unroll
    for (int i = 0; i < 4; i++) {
      float rv = Rs[rg + i][k];
      acc[i][0] += rv * wv.x;
      acc[i][1] += rv * wv.y;
      acc[i][2] += rv * wv.z;
      acc[i][3] += rv * wv.w;
    }
  }
#pragma unroll
  for (int i = 0; i < 4; i++) {
    int r = rg + i;
    if (r < rows) *(float4*)(out + (size_t)(r0 + r) * FEAT + c0) = *(float4*)acc[i];
  }
}

// ---------------- launcher ----------------

extern "C" void kernel_launch(void* const* d_in, const int* in_sizes, int n_in,
                              void* d_out, int out_size, void* d_ws, size_t ws_size,
                              hipStream_t stream) {
  const float* h    = (const float*)d_in[0];
  const int*   ids  = (const int*)d_in[1];
  const int*   es   = (const int*)d_in[2];
  const int*   ed   = (const int*)d_in[3];
  const float* mask = (const float*)d_in[4];
  const float* W    = (const float*)d_in[5];
  const float* b    = (const float*)d_in[6];
  float* out = (float*)d_out;

  const int NS = in_sizes[1];               // 200000 src nodes
  const int E  = in_sizes[2];               // 1.6M edges
  const int H  = in_sizes[6];               // 128
  const int ND = (out_size - NS) / H;       // 50000 dst nodes

  // mask_values output region doubles as softmax scratch (gather -> exp -> normalize, in place)
  float* mv = out + (size_t)ND * H;

  // workspace carve (~7.5 MB)
  char* w = (char*)d_ws;
  auto carve = [&](size_t bytes) -> char* {
    char* p = w;
    w += (bytes + 255) & ~(size_t)255;
    return p;
  };
  float* pbuf = (float*)carve(4096 * sizeof(float));
  float* gmax = (float*)carve(256);
  float* ginv = (float*)carve(256);
  int* deg = (int*)carve((size_t)ND * sizeof(int));
  int* cur = (int*)carve((size_t)ND * sizeof(int));
  int* rp  = (int*)carve((size_t)(ND + 1) * sizeof(int));
  int* csr = (int*)carve((size_t)E * sizeof(int));

  hipMemsetAsync(deg, 0, (size_t)ND * sizeof(int), stream);
  hipMemsetAsync(cur, 0, (size_t)ND * sizeof(int), stream);

  const int gb = (NS + 255) / 256;
  k_gather_max<<<gb, 256, 0, stream>>>(mask, ids, mv, pbuf, NS);
  k_reduce_max<<<1, 1024, 0, stream>>>(pbuf, gmax, gb);
  k_exp_sum<<<gb, 256, 0, stream>>>(mv, gmax, pbuf, NS);
  k_reduce_sum<<<1, 1024, 0, stream>>>(pbuf, ginv, gb);
  k_normalize<<<gb, 256, 0, stream>>>(mv, ginv, NS);

  k_deg<<<(E + 255) / 256, 256, 0, stream>>>(ed, deg, E);
  k_scan<<<1, 1024, 0, stream>>>(deg, rp, ND);
  k_scatter<<<(E + 255) / 256, 256, 0, stream>>>(es, ed, rp, cur, csr, E);

  k_agg<<<ND, 64, 0, stream>>>(rp, csr, h, mv, out);
  k_gemm<<<(ND + 31) / 32, 256, 0, stream>>>(out, W, b, ND);
}